// Round 2
// baseline (675.422 us; speedup 1.0000x reference)
//
#include <hip/hip_runtime.h>
#include <math.h>

#define N_ 128
#define I_ 256
#define O_ 256
#define P_ 16
#define OT 8      // o's per block
#define IT 8      // i's per block
#define SQRT_2PI 2.5066282746310002f
#define INV_SQRT_2PI 0.3989422804014327f

// grid: 32 o-tiles * 32 i-ranges = 1024 blocks, 256 threads each (4 blocks/CU).
// Each block: 8 o's, 8 i's, all 128 n. Phase A sets up 2 i's at a time using
// all 256 threads (16 groups of 16 lanes). Accumulate in regs, atomicAdd once.
__global__ __launch_bounds__(256, 4) void gp_fused(
    const float* __restrict__ x_mean, const float* __restrict__ x_var,
    const float* __restrict__ z_param, const float* __restrict__ h,
    const float* __restrict__ l_param, const float* __restrict__ s_param,
    const float* __restrict__ jitter_param, float* __restrict__ out)
{
    __shared__ float xm_s[N_][IT + 1];
    __shared__ float xv_s[N_][IT + 1];
    __shared__ float LinvS[2][OT][P_][P_ + 1];   // +1 pad: write conflicts 4->2 way
    __shared__ float zS[2][OT][P_];
    __shared__ float wS[2][OT][P_];
    __shared__ float scS[2][OT][2];              // l2, s^2*l

    const int t = threadIdx.x;
    const int b = blockIdx.x;
    const int ot = b & 31;         // 32 o-tiles
    const int ir = b >> 5;         // 32 i-ranges
    const int o_base = ot * OT;
    const int i0 = ir * IT;

    // ---- stage x slice (coalesced float4 loads, once per block) ----
    {
        const int vidx = t;                 // exactly N_*IT/4 == 256
        const int n = vidx >> 1, q = vidx & 1;
        const float4 xm4 = *(const float4*)(x_mean + n * I_ + i0 + q * 4);
        const float4 xv4 = *(const float4*)(x_var  + n * I_ + i0 + q * 4);
        xm_s[n][q*4+0] = xm4.x; xm_s[n][q*4+1] = xm4.y;
        xm_s[n][q*4+2] = xm4.z; xm_s[n][q*4+3] = xm4.w;
        xv_s[n][q*4+0] = xv4.x; xv_s[n][q*4+1] = xv4.y;
        xv_s[n][q*4+2] = xv4.z; xv_s[n][q*4+3] = xv4.w;
    }
    __syncthreads();

    float am[4] = {0.f, 0.f, 0.f, 0.f};
    float av[4] = {IT * 0.1f, IT * 0.1f, IT * 0.1f, IT * 0.1f}; // GLOBAL_JITTER per i

    const int ol = t >> 5;   // phase B: o_local (0..7), 32 threads each
    const int ln = t & 31;
    const int g2 = t >> 4;   // phase A: group 0..15
    const int il = g2 >> 3;  // which i of the pair
    const int g  = g2 & 7;   // o group
    const int p  = t & 15;   // lane-in-group

    for (int ii2 = 0; ii2 < IT / 2; ++ii2) {

        // ======== Phase A: per-pair setup for 2 i's (all 256 threads) =======
        {
            const int i  = i0 + ii2 * 2 + il;
            const int o  = o_base + g;
            const int io = i * O_ + o;
            const float l   = expf(l_param[io]) + 0.2f;
            const float s   = expf(s_param[io]) + 0.1f;
            const float jit = expf(jitter_param[io]) + 0.01f;
            const float l2 = l * l;
            const float inv2l2 = 0.5f / l2;
            const float cQ = INV_SQRT_2PI / l;
            const float noise = jit * jit / (s * s * l * SQRT_2PI);

            const float zp = tanhf(z_param[io * P_ + p]);

            // build row p of Q (row-per-lane)
            float a[P_];
            #pragma unroll
            for (int c = 0; c < P_; ++c) {
                const float zc = __shfl(zp, c, P_);
                const float d = zp - zc;
                a[c] = cQ * __expf(-d * d * inv2l2) + ((c == p) ? noise : 0.0f);
            }

            // in-register Cholesky (row-per-lane, static indices only)
            #pragma unroll
            for (int k = 0; k < P_; ++k) {
                const float akk = __shfl(a[k], k, P_);
                const float lkk = sqrtf(akk);
                const float inv_lkk = 1.0f / lkk;
                if (p == k)      a[k] = lkk;
                else if (p > k)  a[k] *= inv_lkk;
                const float lrk = a[k];   // own L[p][k] (valid for p>=k)
                #pragma unroll
                for (int c = k + 1; c < P_; ++c) {
                    const float lck = __shfl(a[k], c, P_);  // L[c][k]
                    if (p >= c) a[c] -= lrk * lck;
                }
            }

            // M = L^-1, column-per-lane (lane p computes column p)
            float x[P_];
            #pragma unroll
            for (int r = 0; r < P_; ++r) {
                const float lrr = __shfl(a[r], r, P_);
                float acc = (r == p) ? 1.0f : 0.0f;
                #pragma unroll
                for (int m = 0; m < r; ++m) {
                    const float lrm = __shfl(a[m], r, P_);  // L[r][m]
                    acc -= lrm * x[m];
                }
                x[r] = acc / lrr;   // exactly 0 for r < p
            }

            // w = M^T (M h)
            const float hc = h[io * P_ + p];
            float y[P_];
            #pragma unroll
            for (int r = 0; r < P_; ++r) y[r] = x[r] * hc;
            #pragma unroll
            for (int off = 8; off >= 1; off >>= 1) {
                #pragma unroll
                for (int r = 0; r < P_; ++r) y[r] += __shfl_xor(y[r], off, P_);
            }
            float wc = 0.f;
            #pragma unroll
            for (int r = 0; r < P_; ++r) wc += x[r] * y[r];

            // publish to LDS
            #pragma unroll
            for (int r = 0; r < P_; ++r) LinvS[il][g][r][p] = x[r];
            zS[il][g][p] = zp;
            wS[il][g][p] = wc;
            if (p == 0) { scS[il][g][0] = l2; scS[il][g][1] = s * s * l; }
        }
        __syncthreads();

        // ======== Phase B: per-site work (all 256 threads), both i's ========
        #pragma unroll
        for (int il2 = 0; il2 < 2; ++il2) {
            const int iiA = ii2 * 2 + il2;
            const float l2  = scS[il2][ol][0];
            const float s2l = scS[il2][ol][1];
            const float t4v = SQRT_2PI * s2l;
            float zr[P_], wr[P_];
            #pragma unroll
            for (int r = 0; r < P_; ++r) { zr[r] = zS[il2][ol][r]; wr[r] = wS[il2][ol][r]; }

            #pragma unroll
            for (int j = 0; j < 4; ++j) {
                const int n = ln + 32 * j;
                const float xm = xm_s[n][iiA];
                const float xv = xv_s[n][iiA];
                const float v = xv + l2;
                const float h2v = 0.5f / v;
                const float cc = rsqrtf(v) * INV_SQRT_2PI;

                float e[P_];
                float dm = 0.f;
                #pragma unroll
                for (int pp = 0; pp < P_; ++pp) {
                    const float d = xm - zr[pp];
                    e[pp] = __expf(-d * d * h2v);
                    dm += e[pp] * wr[pp];
                }

                float su = 0.f;
                #pragma unroll
                for (int r = 0; r < P_; ++r) {
                    float ur = 0.f;
                    #pragma unroll
                    for (int m = 0; m <= r; ++m) ur += LinvS[il2][ol][r][m] * e[m];
                    su += ur * ur;
                }

                am[j] += cc * dm;
                const float t3 = s2l * rsqrtf(l2 + 2.f * xv);
                av[j] += t3 - t4v * (cc * cc) * su;
            }
        }
        __syncthreads();
    }

    // ---- accumulate into output (32 i-range blocks contend per address) ----
    const int o = o_base + ol;
    #pragma unroll
    for (int j = 0; j < 4; ++j) {
        const int n = ln + 32 * j;
        atomicAdd(out + n * O_ + o, am[j]);
        atomicAdd(out + N_ * O_ + n * O_ + o, av[j]);
    }
}

extern "C" void kernel_launch(void* const* d_in, const int* in_sizes, int n_in,
                              void* d_out, int out_size, void* d_ws, size_t ws_size,
                              hipStream_t stream) {
    const float* x_mean = (const float*)d_in[0];
    const float* x_var  = (const float*)d_in[1];
    const float* z_param = (const float*)d_in[2];
    const float* h       = (const float*)d_in[3];
    const float* l_param = (const float*)d_in[4];
    const float* s_param = (const float*)d_in[5];
    const float* jitter_param = (const float*)d_in[6];
    float* out = (float*)d_out;

    hipMemsetAsync(d_out, 0, (size_t)out_size * sizeof(float), stream);
    gp_fused<<<dim3(1024), dim3(256), 0, stream>>>(
        x_mean, x_var, z_param, h, l_param, s_param, jitter_param, out);
}

// Round 3
// 266.607 us; speedup vs baseline: 2.5334x; 2.5334x over previous
//
#include <hip/hip_runtime.h>
#include <math.h>

#define N_ 128
#define I_ 256
#define O_ 256
#define P_ 16
#define OT 8      // o's per block
#define IT 8      // i's per block
#define SQRT_2PI 2.5066282746310002f
#define INV_SQRT_2PI 0.3989422804014327f

// grid: 32 o-tiles * 32 i-ranges = 1024 blocks, 256 threads each.
// Each block: 8 o's, 8 i's, all 128 n. Phase A sets up 2 i's at a time using
// all 256 threads (16 groups of 16 lanes). Accumulate in regs, atomicAdd once.
// NOTE: __launch_bounds__(256,2) — NOT 4: forcing 4 waves/EU caps VGPR at 64
// and spills ~600 MB to scratch (R2 regression: 675us, FETCH 663MB). At the
// natural 128 VGPR the HW already permits 4 waves/SIMD.
__global__ __launch_bounds__(256, 2) void gp_fused(
    const float* __restrict__ x_mean, const float* __restrict__ x_var,
    const float* __restrict__ z_param, const float* __restrict__ h,
    const float* __restrict__ l_param, const float* __restrict__ s_param,
    const float* __restrict__ jitter_param, float* __restrict__ out)
{
    __shared__ float xm_s[N_][IT + 1];
    __shared__ float xv_s[N_][IT + 1];
    __shared__ float LinvS[2][OT][P_][P_ + 1];   // +1 pad: write conflicts 4->2 way
    __shared__ float zS[2][OT][P_];
    __shared__ float wS[2][OT][P_];
    __shared__ float scS[2][OT][2];              // l2, s^2*l

    const int t = threadIdx.x;
    const int b = blockIdx.x;
    const int ot = b & 31;         // 32 o-tiles
    const int ir = b >> 5;         // 32 i-ranges
    const int o_base = ot * OT;
    const int i0 = ir * IT;

    // ---- stage x slice (coalesced float4 loads, once per block) ----
    {
        const int vidx = t;                 // exactly N_*IT/4 == 256
        const int n = vidx >> 1, q = vidx & 1;
        const float4 xm4 = *(const float4*)(x_mean + n * I_ + i0 + q * 4);
        const float4 xv4 = *(const float4*)(x_var  + n * I_ + i0 + q * 4);
        xm_s[n][q*4+0] = xm4.x; xm_s[n][q*4+1] = xm4.y;
        xm_s[n][q*4+2] = xm4.z; xm_s[n][q*4+3] = xm4.w;
        xv_s[n][q*4+0] = xv4.x; xv_s[n][q*4+1] = xv4.y;
        xv_s[n][q*4+2] = xv4.z; xv_s[n][q*4+3] = xv4.w;
    }
    __syncthreads();

    float am[4] = {0.f, 0.f, 0.f, 0.f};
    float av[4] = {IT * 0.1f, IT * 0.1f, IT * 0.1f, IT * 0.1f}; // GLOBAL_JITTER per i

    const int ol = t >> 5;   // phase B: o_local (0..7), 32 threads each
    const int ln = t & 31;
    const int g2 = t >> 4;   // phase A: group 0..15
    const int il = g2 >> 3;  // which i of the pair
    const int g  = g2 & 7;   // o group
    const int p  = t & 15;   // lane-in-group

    for (int ii2 = 0; ii2 < IT / 2; ++ii2) {

        // ======== Phase A: per-pair setup for 2 i's (all 256 threads) =======
        {
            const int i  = i0 + ii2 * 2 + il;
            const int o  = o_base + g;
            const int io = i * O_ + o;
            const float l   = expf(l_param[io]) + 0.2f;
            const float s   = expf(s_param[io]) + 0.1f;
            const float jit = expf(jitter_param[io]) + 0.01f;
            const float l2 = l * l;
            const float inv2l2 = 0.5f / l2;
            const float cQ = INV_SQRT_2PI / l;
            const float noise = jit * jit / (s * s * l * SQRT_2PI);

            const float zp = tanhf(z_param[io * P_ + p]);

            // build row p of Q (row-per-lane)
            float a[P_];
            #pragma unroll
            for (int c = 0; c < P_; ++c) {
                const float zc = __shfl(zp, c, P_);
                const float d = zp - zc;
                a[c] = cQ * __expf(-d * d * inv2l2) + ((c == p) ? noise : 0.0f);
            }

            // in-register Cholesky (row-per-lane, static indices only)
            #pragma unroll
            for (int k = 0; k < P_; ++k) {
                const float akk = __shfl(a[k], k, P_);
                const float lkk = sqrtf(akk);
                const float inv_lkk = 1.0f / lkk;
                if (p == k)      a[k] = lkk;
                else if (p > k)  a[k] *= inv_lkk;
                const float lrk = a[k];   // own L[p][k] (valid for p>=k)
                #pragma unroll
                for (int c = k + 1; c < P_; ++c) {
                    const float lck = __shfl(a[k], c, P_);  // L[c][k]
                    if (p >= c) a[c] -= lrk * lck;
                }
            }

            // M = L^-1, column-per-lane (lane p computes column p)
            float x[P_];
            #pragma unroll
            for (int r = 0; r < P_; ++r) {
                const float lrr = __shfl(a[r], r, P_);
                float acc = (r == p) ? 1.0f : 0.0f;
                #pragma unroll
                for (int m = 0; m < r; ++m) {
                    const float lrm = __shfl(a[m], r, P_);  // L[r][m]
                    acc -= lrm * x[m];
                }
                x[r] = acc / lrr;   // exactly 0 for r < p
            }

            // w = M^T (M h)
            const float hc = h[io * P_ + p];
            float y[P_];
            #pragma unroll
            for (int r = 0; r < P_; ++r) y[r] = x[r] * hc;
            #pragma unroll
            for (int off = 8; off >= 1; off >>= 1) {
                #pragma unroll
                for (int r = 0; r < P_; ++r) y[r] += __shfl_xor(y[r], off, P_);
            }
            float wc = 0.f;
            #pragma unroll
            for (int r = 0; r < P_; ++r) wc += x[r] * y[r];

            // publish to LDS
            #pragma unroll
            for (int r = 0; r < P_; ++r) LinvS[il][g][r][p] = x[r];
            zS[il][g][p] = zp;
            wS[il][g][p] = wc;
            if (p == 0) { scS[il][g][0] = l2; scS[il][g][1] = s * s * l; }
        }
        __syncthreads();

        // ======== Phase B: per-site work (all 256 threads), both i's ========
        #pragma unroll
        for (int il2 = 0; il2 < 2; ++il2) {
            const int iiA = ii2 * 2 + il2;
            const float l2  = scS[il2][ol][0];
            const float s2l = scS[il2][ol][1];
            const float t4v = SQRT_2PI * s2l;
            float zr[P_], wr[P_];
            #pragma unroll
            for (int r = 0; r < P_; ++r) { zr[r] = zS[il2][ol][r]; wr[r] = wS[il2][ol][r]; }

            #pragma unroll
            for (int j = 0; j < 4; ++j) {
                const int n = ln + 32 * j;
                const float xm = xm_s[n][iiA];
                const float xv = xv_s[n][iiA];
                const float v = xv + l2;
                const float h2v = 0.5f / v;
                const float cc = rsqrtf(v) * INV_SQRT_2PI;

                float e[P_];
                float dm = 0.f;
                #pragma unroll
                for (int pp = 0; pp < P_; ++pp) {
                    const float d = xm - zr[pp];
                    e[pp] = __expf(-d * d * h2v);
                    dm += e[pp] * wr[pp];
                }

                float su = 0.f;
                #pragma unroll
                for (int r = 0; r < P_; ++r) {
                    float ur = 0.f;
                    #pragma unroll
                    for (int m = 0; m <= r; ++m) ur += LinvS[il2][ol][r][m] * e[m];
                    su += ur * ur;
                }

                am[j] += cc * dm;
                const float t3 = s2l * rsqrtf(l2 + 2.f * xv);
                av[j] += t3 - t4v * (cc * cc) * su;
            }
        }
        __syncthreads();
    }

    // ---- accumulate into output (32 i-range blocks contend per address) ----
    const int o = o_base + ol;
    #pragma unroll
    for (int j = 0; j < 4; ++j) {
        const int n = ln + 32 * j;
        atomicAdd(out + n * O_ + o, am[j]);
        atomicAdd(out + N_ * O_ + n * O_ + o, av[j]);
    }
}

extern "C" void kernel_launch(void* const* d_in, const int* in_sizes, int n_in,
                              void* d_out, int out_size, void* d_ws, size_t ws_size,
                              hipStream_t stream) {
    const float* x_mean = (const float*)d_in[0];
    const float* x_var  = (const float*)d_in[1];
    const float* z_param = (const float*)d_in[2];
    const float* h       = (const float*)d_in[3];
    const float* l_param = (const float*)d_in[4];
    const float* s_param = (const float*)d_in[5];
    const float* jitter_param = (const float*)d_in[6];
    float* out = (float*)d_out;

    hipMemsetAsync(d_out, 0, (size_t)out_size * sizeof(float), stream);
    gp_fused<<<dim3(1024), dim3(256), 0, stream>>>(
        x_mean, x_var, z_param, h, l_param, s_param, jitter_param, out);
}

// Round 4
// 264.863 us; speedup vs baseline: 2.5501x; 1.0066x over previous
//
#include <hip/hip_runtime.h>
#include <math.h>

#define N_ 128
#define I_ 256
#define O_ 256
#define P_ 16
#define OT 8      // o's per block
#define IT 8      // i's per block
#define SQRT_2PI 2.5066282746310002f
#define INV_SQRT_2PI 0.3989422804014327f

// grid: 32 o-tiles * 32 i-ranges = 1024 blocks, 256 threads each.
// Phase A: 2 i's at a time, 16 groups x 16 lanes, in-register Cholesky+inv.
// Phase B: m-outer matvec — column m of L^-1 read ONCE per wave as b128
// (broadcast), applied to 4 sites/lane from register accumulators u[4][16].
// R3 lesson: scalar ds_read per FMA made phase B LDS-pipe-bound (54% VALU).
// R2 lesson: do NOT force __launch_bounds__ min-waves=4 (VGPR cap 64 -> spill).
__global__ __launch_bounds__(256, 2) void gp_fused(
    const float* __restrict__ x_mean, const float* __restrict__ x_var,
    const float* __restrict__ z_param, const float* __restrict__ h,
    const float* __restrict__ l_param, const float* __restrict__ s_param,
    const float* __restrict__ jitter_param, float* __restrict__ out)
{
    __shared__ float xm_s[N_][IT + 1];
    __shared__ float xv_s[N_][IT + 1];
    __shared__ __align__(16) float LinvT[2][OT][P_][P_];  // [il][o][col][row]
    __shared__ __align__(16) float zS[2][OT][P_];
    __shared__ __align__(16) float wS[2][OT][P_];
    __shared__ float scS[2][OT][2];              // l2, s^2*l

    const int t = threadIdx.x;
    const int b = blockIdx.x;
    const int ot = b & 31;         // 32 o-tiles
    const int ir = b >> 5;         // 32 i-ranges
    const int o_base = ot * OT;
    const int i0 = ir * IT;

    // ---- stage x slice (coalesced float4 loads, once per block) ----
    {
        const int n = t >> 1, q = t & 1;
        const float4 xm4 = *(const float4*)(x_mean + n * I_ + i0 + q * 4);
        const float4 xv4 = *(const float4*)(x_var  + n * I_ + i0 + q * 4);
        xm_s[n][q*4+0] = xm4.x; xm_s[n][q*4+1] = xm4.y;
        xm_s[n][q*4+2] = xm4.z; xm_s[n][q*4+3] = xm4.w;
        xv_s[n][q*4+0] = xv4.x; xv_s[n][q*4+1] = xv4.y;
        xv_s[n][q*4+2] = xv4.z; xv_s[n][q*4+3] = xv4.w;
    }
    __syncthreads();

    float am[4] = {0.f, 0.f, 0.f, 0.f};
    float av[4] = {IT * 0.1f, IT * 0.1f, IT * 0.1f, IT * 0.1f}; // GLOBAL_JITTER per i

    const int ol = t >> 5;   // phase B: o_local (0..7), 32 threads each
    const int ln = t & 31;
    const int g2 = t >> 4;   // phase A: group 0..15
    const int il = g2 >> 3;  // which i of the pair
    const int g  = g2 & 7;   // o group
    const int p  = t & 15;   // lane-in-group

    for (int ii2 = 0; ii2 < IT / 2; ++ii2) {

        // ======== Phase A: per-pair setup for 2 i's (all 256 threads) =======
        {
            const int i  = i0 + ii2 * 2 + il;
            const int o  = o_base + g;
            const int io = i * O_ + o;
            const float l   = expf(l_param[io]) + 0.2f;
            const float s   = expf(s_param[io]) + 0.1f;
            const float jit = expf(jitter_param[io]) + 0.01f;
            const float l2 = l * l;
            const float inv2l2 = 0.5f / l2;
            const float cQ = INV_SQRT_2PI / l;
            const float noise = jit * jit / (s * s * l * SQRT_2PI);

            const float zp = tanhf(z_param[io * P_ + p]);

            // build row p of Q (row-per-lane)
            float a[P_];
            #pragma unroll
            for (int c = 0; c < P_; ++c) {
                const float zc = __shfl(zp, c, P_);
                const float d = zp - zc;
                a[c] = cQ * __expf(-d * d * inv2l2) + ((c == p) ? noise : 0.0f);
            }

            // in-register Cholesky (row-per-lane, static indices only)
            #pragma unroll
            for (int k = 0; k < P_; ++k) {
                const float akk = __shfl(a[k], k, P_);
                const float lkk = sqrtf(akk);
                const float inv_lkk = 1.0f / lkk;
                if (p == k)      a[k] = lkk;
                else if (p > k)  a[k] *= inv_lkk;
                const float lrk = a[k];   // own L[p][k] (valid for p>=k)
                #pragma unroll
                for (int c = k + 1; c < P_; ++c) {
                    const float lck = __shfl(a[k], c, P_);  // L[c][k]
                    if (p >= c) a[c] -= lrk * lck;
                }
            }

            // M = L^-1, column-per-lane (lane p computes column p)
            float x[P_];
            #pragma unroll
            for (int r = 0; r < P_; ++r) {
                const float lrr = __shfl(a[r], r, P_);
                float acc = (r == p) ? 1.0f : 0.0f;
                #pragma unroll
                for (int m = 0; m < r; ++m) {
                    const float lrm = __shfl(a[m], r, P_);  // L[r][m]
                    acc -= lrm * x[m];
                }
                x[r] = acc / lrr;   // exactly 0 for r < p
            }

            // w = M^T (M h)
            const float hc = h[io * P_ + p];
            float y[P_];
            #pragma unroll
            for (int r = 0; r < P_; ++r) y[r] = x[r] * hc;
            #pragma unroll
            for (int off = 8; off >= 1; off >>= 1) {
                #pragma unroll
                for (int r = 0; r < P_; ++r) y[r] += __shfl_xor(y[r], off, P_);
            }
            float wc = 0.f;
            #pragma unroll
            for (int r = 0; r < P_; ++r) wc += x[r] * y[r];

            // publish to LDS: lane p writes COLUMN p contiguously (4x b128)
            float4* dst = (float4*)&LinvT[il][g][p][0];
            dst[0] = make_float4(x[ 0], x[ 1], x[ 2], x[ 3]);
            dst[1] = make_float4(x[ 4], x[ 5], x[ 6], x[ 7]);
            dst[2] = make_float4(x[ 8], x[ 9], x[10], x[11]);
            dst[3] = make_float4(x[12], x[13], x[14], x[15]);
            zS[il][g][p] = zp;
            wS[il][g][p] = wc;
            if (p == 0) { scS[il][g][0] = l2; scS[il][g][1] = s * s * l; }
        }
        __syncthreads();

        // ======== Phase B: per-site work (all 256 threads), both i's ========
        #pragma unroll
        for (int il2 = 0; il2 < 2; ++il2) {
            const int iiA = ii2 * 2 + il2;
            const float l2  = scS[il2][ol][0];
            const float s2l = scS[il2][ol][1];
            const float t4v = SQRT_2PI * s2l;

            float zr[P_], wr[P_];
            {
                const float4* zp4 = (const float4*)&zS[il2][ol][0];
                const float4* wp4 = (const float4*)&wS[il2][ol][0];
                #pragma unroll
                for (int c = 0; c < 4; ++c) {
                    const float4 z4 = zp4[c], w4 = wp4[c];
                    zr[4*c+0] = z4.x; zr[4*c+1] = z4.y; zr[4*c+2] = z4.z; zr[4*c+3] = z4.w;
                    wr[4*c+0] = w4.x; wr[4*c+1] = w4.y; wr[4*c+2] = w4.z; wr[4*c+3] = w4.w;
                }
            }

            float xm[4], xv[4], cc[4], nh[4], dm[4];
            #pragma unroll
            for (int j = 0; j < 4; ++j) {
                const int n = ln + 32 * j;
                xm[j] = xm_s[n][iiA];
                xv[j] = xv_s[n][iiA];
                const float v = xv[j] + l2;
                cc[j] = rsqrtf(v) * INV_SQRT_2PI;
                nh[j] = -0.5f / v;
                dm[j] = 0.f;
            }

            float u[4][P_];   // u[j][r] = (L^-1 e_j)[r], accumulated m-outer
            #pragma unroll
            for (int m = 0; m < P_; ++m) {
                float em[4];
                #pragma unroll
                for (int j = 0; j < 4; ++j) {
                    const float d = xm[j] - zr[m];
                    em[j] = __expf(d * d * nh[j]);
                    dm[j] += em[j] * wr[m];
                }
                const int c0 = m >> 2;   // static after unroll
                #pragma unroll
                for (int c = 0; c < 4; ++c) {
                    if (c < c0) continue;  // rows above (aligned) diag chunk: skip
                    const float4 L4 = *(const float4*)&LinvT[il2][ol][m][4*c];
                    #pragma unroll
                    for (int j = 0; j < 4; ++j) {
                        if (m == 0) {
                            u[j][4*c+0] = L4.x * em[j];
                            u[j][4*c+1] = L4.y * em[j];
                            u[j][4*c+2] = L4.z * em[j];
                            u[j][4*c+3] = L4.w * em[j];
                        } else {
                            u[j][4*c+0] += L4.x * em[j];
                            u[j][4*c+1] += L4.y * em[j];
                            u[j][4*c+2] += L4.z * em[j];
                            u[j][4*c+3] += L4.w * em[j];
                        }
                    }
                }
            }

            #pragma unroll
            for (int j = 0; j < 4; ++j) {
                float su = 0.f;
                #pragma unroll
                for (int r = 0; r < P_; ++r) su += u[j][r] * u[j][r];
                am[j] += cc[j] * dm[j];
                const float t3 = s2l * rsqrtf(l2 + 2.f * xv[j]);
                av[j] += t3 - t4v * (cc[j] * cc[j]) * su;
            }
        }
        __syncthreads();
    }

    // ---- accumulate into output (32 i-range blocks contend per address) ----
    const int o = o_base + ol;
    #pragma unroll
    for (int j = 0; j < 4; ++j) {
        const int n = ln + 32 * j;
        atomicAdd(out + n * O_ + o, am[j]);
        atomicAdd(out + N_ * O_ + n * O_ + o, av[j]);
    }
}

extern "C" void kernel_launch(void* const* d_in, const int* in_sizes, int n_in,
                              void* d_out, int out_size, void* d_ws, size_t ws_size,
                              hipStream_t stream) {
    const float* x_mean = (const float*)d_in[0];
    const float* x_var  = (const float*)d_in[1];
    const float* z_param = (const float*)d_in[2];
    const float* h       = (const float*)d_in[3];
    const float* l_param = (const float*)d_in[4];
    const float* s_param = (const float*)d_in[5];
    const float* jitter_param = (const float*)d_in[6];
    float* out = (float*)d_out;

    hipMemsetAsync(d_out, 0, (size_t)out_size * sizeof(float), stream);
    gp_fused<<<dim3(1024), dim3(256), 0, stream>>>(
        x_mean, x_var, z_param, h, l_param, s_param, jitter_param, out);
}